// Round 9
// baseline (536.052 us; speedup 1.0000x reference)
//
#include <hip/hip_runtime.h>
#include <stdint.h>

namespace {
constexpr int kNodes = 50000;
constexpr int kEdges = 800000;
constexpr int kHid   = 128;
constexpr int kScanBlocks = (kNodes + 255) / 256;  // 196

// workspace layout (bytes)
constexpr size_t oCounts    = 0;         // 200000 (in-degree per node)
constexpr size_t oCursor    = 200704;    // 200000 (scan -> row_end)
constexpr size_t oBlockSums = 401408;    // 784
constexpr size_t oBpack     = 402432;    // 655360 (packed MFMA B-frags)
constexpr size_t oPacked    = 1057792;   // 800000*4 = 3200000 (CSR edge list)
constexpr size_t oMsg       = 4257792;   // 50000*128*4 = 25600000 (fp32 msg)
constexpr size_t oY         = 29857792;  // 50000*512*2 = 51200000 (bf16 y)
constexpr size_t kWsNeeded   = oY + 51200000;  // 81,057,792
constexpr size_t kWsFallback = oY;             // fallback path doesn't use oY

// Bpack sub-offsets (bytes relative to oBpack)
constexpr size_t bKhi = 0,      bKlo = 98304,  bRhi = 196608,
                 bRlo = 294912, bWhi = 393216, bWlo = 524288;
}

typedef __attribute__((ext_vector_type(8))) short short8;
typedef __attribute__((ext_vector_type(4))) float f32x4;

union ABFrag { short8 v; uint16_t u[8]; uint4 q; };

__device__ __forceinline__ uint16_t f2bf(float x) {
  uint32_t u = __float_as_uint(x);
  return (uint16_t)((u + 0x7FFFu + ((u >> 16) & 1u)) >> 16);
}
__device__ __forceinline__ float bf2f(uint16_t h) {
  return __uint_as_float(((uint32_t)h) << 16);
}

__device__ __forceinline__ float fast_rcp(float x) {
#if __has_builtin(__builtin_amdgcn_rcpf)
  return __builtin_amdgcn_rcpf(x);
#else
  return 1.f / x;
#endif
}
__device__ __forceinline__ float fast_exp2(float x) {
#if __has_builtin(__builtin_amdgcn_exp2f)
  return __builtin_amdgcn_exp2f(x);
#else
  return exp2f(x);
#endif
}
__device__ __forceinline__ float sigf(float x) {
  return fast_rcp(1.f + fast_exp2(-1.4426950408889634f * x));
}
__device__ __forceinline__ float tanh_fast(float x) {
  x = fminf(fmaxf(x, -10.f), 10.f);
  const float t = fast_exp2(2.8853900817779268f * x);  // e^(2x)
  return (t - 1.f) * fast_rcp(t + 1.f);
}

// msg/y column swizzle: position p holds original column pi(p).
// p = g*64 + col16*4 + s  <->  pi(p) = g*64 + s*16 + col16  (bijection on [0,128))
__device__ __forceinline__ int swz_pi(int p) {
  return (p & 64) | ((p & 3) << 4) | ((p >> 2) & 15);
}

// ---------------- CSR build ----------------

__global__ __launch_bounds__(256) void count_kernel(const int* __restrict__ edges,
                                                    int* __restrict__ counts) {
  int e = blockIdx.x * 256 + threadIdx.x;
  if (e < kEdges) atomicAdd(&counts[edges[e * 3 + 2]], 1);
}

__global__ __launch_bounds__(256) void scan1_kernel(const int* __restrict__ counts,
                                                    int* __restrict__ cursor,
                                                    int* __restrict__ blocksums) {
  __shared__ int sd[256];
  const int t = threadIdx.x;
  const int i = blockIdx.x * 256 + t;
  int v = (i < kNodes) ? counts[i] : 0;
  sd[t] = v;
  __syncthreads();
  for (int off = 1; off < 256; off <<= 1) {
    int x = (t >= off) ? sd[t - off] : 0;
    __syncthreads();
    sd[t] += x;
    __syncthreads();
  }
  if (i < kNodes) cursor[i] = sd[t] - v;
  if (t == 255) blocksums[blockIdx.x] = sd[255];
}

__global__ __launch_bounds__(256) void scan2_kernel(int* __restrict__ blocksums) {
  __shared__ int sd[256];
  const int t = threadIdx.x;
  int v = (t < kScanBlocks) ? blocksums[t] : 0;
  sd[t] = v;
  __syncthreads();
  for (int off = 1; off < 256; off <<= 1) {
    int x = (t >= off) ? sd[t - off] : 0;
    __syncthreads();
    sd[t] += x;
    __syncthreads();
  }
  if (t < kScanBlocks) blocksums[t] = sd[t] - v;
}

__global__ __launch_bounds__(256) void scan3_kernel(int* __restrict__ cursor,
                                                    const int* __restrict__ blocksums) {
  const int i = blockIdx.x * 256 + threadIdx.x;
  if (i < kNodes) cursor[i] += blocksums[blockIdx.x];
}

__global__ __launch_bounds__(256) void fill_kernel(const int* __restrict__ edges,
                                                   int* __restrict__ cursor,
                                                   unsigned* __restrict__ packed) {
  int e = blockIdx.x * 256 + threadIdx.x;
  if (e < kEdges) {
    const int et  = edges[e * 3 + 0];
    const int src = edges[e * 3 + 1];
    const int tgt = edges[e * 3 + 2];
    const int pos = atomicAdd(&cursor[tgt], 1);
    packed[pos] = (unsigned)(src * 4 + et);
  }
  // after this kernel cursor[v] = row_end(v)
}

// ---------------- pack B operands into MFMA-frag order ----------------
// K (msg-side) k-rows permuted by swz_pi to match the swizzled msg layout.
__global__ __launch_bounds__(256) void pack_b_kernel(
    const float* __restrict__ K,   // [128][384]
    const float* __restrict__ R,   // [128][384]
    const float* __restrict__ W,   // [4][128][128]
    uint16_t* __restrict__ bp) {
  const int idx = blockIdx.x * 256 + threadIdx.x;
  uint16_t* khi = bp + bKhi / 2;
  uint16_t* klo = bp + bKlo / 2;
  uint16_t* rhi = bp + bRhi / 2;
  uint16_t* rlo = bp + bRlo / 2;
  uint16_t* whi = bp + bWhi / 2;
  uint16_t* wlo = bp + bWlo / 2;
  if (idx < 128 * 384) {
    const int k = idx / 384, c = idx % 384;
    const int ksrc = swz_pi(k);
    const int kt = k >> 5, quad = (k >> 3) & 3, j = k & 7;
    const int nt = c >> 4, ln = (c & 15) | (quad << 4);
    const size_t o = ((size_t)(kt * 24 + nt) * 64 + ln) * 8 + j;
    const float kv = K[ksrc * 384 + c];
    const float rv = R[k * 384 + c];
    const uint16_t kh = f2bf(kv), rh = f2bf(rv);
    khi[o] = kh; klo[o] = f2bf(kv - bf2f(kh));
    rhi[o] = rh; rlo[o] = f2bf(rv - bf2f(rh));
  } else if (idx < 128 * 384 + 128 * 512) {
    const int i2 = idx - 128 * 384;
    const int k = i2 / 512, c = i2 % 512;
    const int t = c >> 7, cc = c & 127;
    const float wv = W[((size_t)t * 128 + k) * 128 + cc];
    const int kt = k >> 5, quad = (k >> 3) & 3, j = k & 7;
    const int nt = c >> 4, ln = (c & 15) | (quad << 4);
    const size_t o = ((size_t)(kt * 32 + nt) * 64 + ln) * 8 + j;
    const uint16_t wh = f2bf(wv);
    whi[o] = wh; wlo[o] = f2bf(wv - bf2f(wh));
  }
}

__device__ __forceinline__ void split8(const float* p, ABFrag& hi, ABFrag& lo) {
  const float4 a0 = *(const float4*)p;
  const float4 a1 = *(const float4*)(p + 4);
  const float v[8] = {a0.x, a0.y, a0.z, a0.w, a1.x, a1.y, a1.z, a1.w};
#pragma unroll
  for (int j = 0; j < 8; ++j) {
    const uint16_t t = f2bf(v[j]);
    hi.u[j] = t; lo.u[j] = f2bf(v[j] - bf2f(t));
  }
}
__device__ __forceinline__ void conv8(const float* p, ABFrag& hi) {
  const float4 a0 = *(const float4*)p;
  const float4 a1 = *(const float4*)(p + 4);
  const float v[8] = {a0.x, a0.y, a0.z, a0.w, a1.x, a1.y, a1.z, a1.w};
#pragma unroll
  for (int j = 0; j < 8; ++j) hi.u[j] = f2bf(v[j]);
}

// ---------------- transform (MFMA): y = h @ W_t + TB, bf16 out (swizzled cols) ----------------
// block = 512 nodes x 64 cols; wave = 128 nodes (8 M-tiles) x 64 cols (4 nt).
// All 4 waves read the SAME B-fragments (L1-shared); 24 MFMAs per B-pair.
// 3-term split; bit-identical summation order vs round 8.
__global__ __launch_bounds__(256, 2) void transform_mfma(
    const float* __restrict__ h,       // [N][128]
    const uint16_t* __restrict__ bp,
    const float* __restrict__ TB,      // [512]
    uint16_t* __restrict__ y16) {      // [N][512] bf16 (bias included, swizzled)
  const int tid = threadIdx.x;
  const int wv = tid >> 6;             // wave 0..3 -> node sub-slice
  const int lane = tid & 63;
  const int col16 = lane & 15, quad = lane >> 4;
  const int cb = blockIdx.x & 7;       // col chunk
  const int t  = cb >> 1, nh = cb & 1; // type, nt-half
  const int node0 = (blockIdx.x >> 3) * 512 + wv * 128;

  const uint4* __restrict__ Whi = (const uint4*)(bp + bWhi / 2);
  const uint4* __restrict__ Wlo = (const uint4*)(bp + bWlo / 2);

  bool mok[8];
#pragma unroll
  for (int m = 0; m < 8; ++m) mok[m] = (node0 + m * 16) < kNodes;

  f32x4 acc[4][8];   // [nt_local(s)][m]
#pragma unroll
  for (int s = 0; s < 4; ++s)
#pragma unroll
    for (int m = 0; m < 8; ++m) acc[s][m] = (f32x4){0.f, 0.f, 0.f, 0.f};

  const float* hrow = h + (size_t)(node0 + col16) * kHid + quad * 8;

#pragma unroll
  for (int kt = 0; kt < 4; ++kt) {
    ABFrag ah[8], al[8];
#pragma unroll
    for (int m = 0; m < 8; ++m) {
      if (mok[m]) {
        split8(hrow + (size_t)m * 16 * kHid + kt * 32, ah[m], al[m]);
      } else {
        ah[m].q = make_uint4(0, 0, 0, 0); al[m].q = ah[m].q;
      }
    }
#pragma unroll
    for (int s = 0; s < 4; ++s) {
      ABFrag bh, bl;
      bh.q = Whi[(size_t)(kt * 32 + t * 8 + nh * 4 + s) * 64 + lane];
      bl.q = Wlo[(size_t)(kt * 32 + t * 8 + nh * 4 + s) * 64 + lane];
#pragma unroll
      for (int m = 0; m < 8; ++m) {
        f32x4 c = acc[s][m];
        c = __builtin_amdgcn_mfma_f32_16x16x32_bf16(ah[m].v, bh.v, c, 0, 0, 0);
        c = __builtin_amdgcn_mfma_f32_16x16x32_bf16(ah[m].v, bl.v, c, 0, 0, 0);
        c = __builtin_amdgcn_mfma_f32_16x16x32_bf16(al[m].v, bh.v, c, 0, 0, 0);
        acc[s][m] = c;
      }
    }
  }

  // epilogue: swizzled coalesced stores (position t*128 + nh*64 + col16*4 + s
  // holds original col t*128 + (nh*4+s)*16 + col16 — same mapping as round 8).
  float bias[4];
#pragma unroll
  for (int s = 0; s < 4; ++s) bias[s] = TB[t * 128 + (nh * 4 + s) * 16 + col16];
#pragma unroll
  for (int m = 0; m < 8; ++m) {
    if (!mok[m]) continue;
#pragma unroll
    for (int r = 0; r < 4; ++r) {
      const int node = node0 + m * 16 + quad * 4 + r;
      const uint32_t lo = (uint32_t)f2bf(acc[0][m][r] + bias[0]) |
                          ((uint32_t)f2bf(acc[1][m][r] + bias[1]) << 16);
      const uint32_t hi = (uint32_t)f2bf(acc[2][m][r] + bias[2]) |
                          ((uint32_t)f2bf(acc[3][m][r] + bias[3]) << 16);
      *(uint2*)&y16[(size_t)node * 512 + t * 128 + nh * 64 + col16 * 4] =
          make_uint2(lo, hi);
    }
  }
}

// ---------------- gather: msg[v][p] = sum_e y[src_e*4+t_e][p] (positional) ----------------
__global__ __launch_bounds__(256) void gather_kernel(
    const uint32_t* __restrict__ y2,      // y as uint32 pairs: [row][64]
    const uint32_t* __restrict__ packed,
    const int* __restrict__ rowend,
    const int* __restrict__ counts,
    float* __restrict__ msg) {
  const int tid = threadIdx.x;
  const int lane = tid & 63;
  const int v = blockIdx.x * 4 + (tid >> 6);
  const int cnt = counts[v];
  const int s0 = rowend[v] - cnt;
  float a0 = 0.f, a1 = 0.f;
  int e = 0;
  for (; e + 8 <= cnt; e += 8) {
    uint32_t p[8], u[8];
#pragma unroll
    for (int i = 0; i < 8; ++i) p[i] = packed[s0 + e + i];
#pragma unroll
    for (int i = 0; i < 8; ++i) u[i] = y2[(size_t)p[i] * 64 + lane];
#pragma unroll
    for (int i = 0; i < 8; ++i) {
      a0 += __uint_as_float(u[i] << 16);
      a1 += __uint_as_float(u[i] & 0xFFFF0000u);
    }
  }
  for (; e < cnt; ++e) {
    const uint32_t p = packed[s0 + e];
    const uint32_t u = y2[(size_t)p * 64 + lane];
    a0 += __uint_as_float(u << 16);
    a1 += __uint_as_float(u & 0xFFFF0000u);
  }
  *(float2*)&msg[(size_t)v * kHid + lane * 2] = make_float2(a0, a1);
}

// ---------------- GRU (MFMA): block = 512 threads = 128 nodes x all 128 h-cols ----------------
// wave w = 128 nodes (8 M-tiles) x 16 gate-cols (ntc = w); acc = 4 quantities x 8 m.
// All 8 waves read the same A rows (L1-shared); 8 MFMA per B-load.
// msg column-swizzled; K packed k-rows permuted to match. 2-term split on A.
// IN-PLACE (hin == hout on step 2): block reads all 128 cols of its own 128
// rows and writes all 128 cols of those rows; __syncthreads() between K-loop
// and epilogue drains all waves' global reads before any store.
__global__ __launch_bounds__(512, 2) void gru_mfma(
    const float* __restrict__ msg,     // [N][128] (swizzled cols)
    const float* __restrict__ hin,     // [N][128]
    const uint16_t* __restrict__ bp,
    const float* __restrict__ gb,      // [2][384]
    float* __restrict__ hout) {
  const int tid = threadIdx.x;
  const int w = tid >> 6;              // ntc 0..7 -> gate-col chunk
  const int lane = tid & 63;
  const int col16 = lane & 15, quad = lane >> 4;
  const int node0 = blockIdx.x * 128;

  const uint4* __restrict__ Khi = (const uint4*)(bp + bKhi / 2);
  const uint4* __restrict__ Klo = (const uint4*)(bp + bKlo / 2);
  const uint4* __restrict__ Rhi = (const uint4*)(bp + bRhi / 2);
  const uint4* __restrict__ Rlo = (const uint4*)(bp + bRlo / 2);

  bool mok[8];
#pragma unroll
  for (int m = 0; m < 8; ++m) mok[m] = (node0 + m * 16) < kNodes;

  f32x4 aZ[8], aR[8], aX[8], aH[8];  // [m]
#pragma unroll
  for (int m = 0; m < 8; ++m) {
    aZ[m] = (f32x4){0.f, 0.f, 0.f, 0.f};
    aR[m] = aZ[m]; aX[m] = aZ[m]; aH[m] = aZ[m];
  }

  const float* mrow = msg + (size_t)(node0 + col16) * kHid + quad * 8;
  const float* hrow = hin + (size_t)(node0 + col16) * kHid + quad * 8;

#pragma unroll
  for (int kt = 0; kt < 4; ++kt) {
    ABFrag mh[8], hh[8];
#pragma unroll
    for (int m = 0; m < 8; ++m) {
      if (mok[m]) {
        conv8(mrow + (size_t)m * 16 * kHid + kt * 32, mh[m]);
        conv8(hrow + (size_t)m * 16 * kHid + kt * 32, hh[m]);
      } else {
        mh[m].q = make_uint4(0, 0, 0, 0); hh[m].q = mh[m].q;
      }
    }
    const size_t oz = (size_t)(kt * 24 + w) * 64 + lane;
    const size_t orr = (size_t)(kt * 24 + 8 + w) * 64 + lane;
    const size_t oh = (size_t)(kt * 24 + 16 + w) * 64 + lane;
    ABFrag kzh, kzl, rzh, rzl, krh, krl, rrh, rrl, khh, khl, rhh, rhl;
    kzh.q = Khi[oz]; kzl.q = Klo[oz]; rzh.q = Rhi[oz]; rzl.q = Rlo[oz];
    krh.q = Khi[orr]; krl.q = Klo[orr]; rrh.q = Rhi[orr]; rrl.q = Rlo[orr];
    khh.q = Khi[oh]; khl.q = Klo[oh]; rhh.q = Rhi[oh]; rhl.q = Rlo[oh];
#pragma unroll
    for (int m = 0; m < 8; ++m) {
      f32x4 z = aZ[m];
      z = __builtin_amdgcn_mfma_f32_16x16x32_bf16(mh[m].v, kzh.v, z, 0, 0, 0);
      z = __builtin_amdgcn_mfma_f32_16x16x32_bf16(mh[m].v, kzl.v, z, 0, 0, 0);
      z = __builtin_amdgcn_mfma_f32_16x16x32_bf16(hh[m].v, rzh.v, z, 0, 0, 0);
      z = __builtin_amdgcn_mfma_f32_16x16x32_bf16(hh[m].v, rzl.v, z, 0, 0, 0);
      aZ[m] = z;
      f32x4 r = aR[m];
      r = __builtin_amdgcn_mfma_f32_16x16x32_bf16(mh[m].v, krh.v, r, 0, 0, 0);
      r = __builtin_amdgcn_mfma_f32_16x16x32_bf16(mh[m].v, krl.v, r, 0, 0, 0);
      r = __builtin_amdgcn_mfma_f32_16x16x32_bf16(hh[m].v, rrh.v, r, 0, 0, 0);
      r = __builtin_amdgcn_mfma_f32_16x16x32_bf16(hh[m].v, rrl.v, r, 0, 0, 0);
      aR[m] = r;
      f32x4 x = aX[m];
      x = __builtin_amdgcn_mfma_f32_16x16x32_bf16(mh[m].v, khh.v, x, 0, 0, 0);
      x = __builtin_amdgcn_mfma_f32_16x16x32_bf16(mh[m].v, khl.v, x, 0, 0, 0);
      aX[m] = x;
      f32x4 y = aH[m];
      y = __builtin_amdgcn_mfma_f32_16x16x32_bf16(hh[m].v, rhh.v, y, 0, 0, 0);
      y = __builtin_amdgcn_mfma_f32_16x16x32_bf16(hh[m].v, rhl.v, y, 0, 0, 0);
      aH[m] = y;
    }
  }

  // all waves' reads of hin/msg are complete past this point (vmcnt drained)
  __syncthreads();

  // ---- epilogue (wave-column-local): col c = w*16 + col16
  const int c = w * 16 + col16;
  const float bz = gb[c] + gb[384 + c];
  const float br = gb[128 + c] + gb[512 + c];
  const float bx = gb[256 + c];
  const float bh = gb[640 + c];
#pragma unroll
  for (int m = 0; m < 8; ++m) {
    if (!mok[m]) continue;
#pragma unroll
    for (int r = 0; r < 4; ++r) {
      const int node = node0 + m * 16 + quad * 4 + r;
      const float hp = hin[(size_t)node * kHid + c];
      const float z = sigf(aZ[m][r] + bz);
      const float rr = sigf(aR[m][r] + br);
      const float hh = tanh_fast(aX[m][r] + bx + rr * (aH[m][r] + bh));
      hout[(size_t)node * kHid + c] = z * hp + (1.f - z) * hh;
    }
  }
}

// ---------------- fallback path (only if ws too small) ----------------

__global__ __launch_bounds__(256, 2) void message_fb_kernel(
    const float* __restrict__ hin,
    const unsigned* __restrict__ packed,
    const int* __restrict__ rowend,
    const int* __restrict__ counts,
    const float* __restrict__ W,
    const float* __restrict__ TB,
    float* __restrict__ msg) {
  __shared__ float S[32 * 512];
  __shared__ int D[32][4];
  const int tid = threadIdx.x;
  {
    const int g = tid >> 7;
    const int j = tid & 127;
    for (int i = 0; i < 16; ++i) {
      const int nl = g * 16 + i;
      const int v = blockIdx.x * 32 + nl;
      if (v >= kNodes) break;
      const int cnt = counts[v];
      const int s0 = rowend[v] - cnt;
      float a0 = 0.f, a1 = 0.f, a2 = 0.f, a3 = 0.f;
      int d0 = 0, d1 = 0, d2 = 0, d3 = 0;
      for (int e = 0; e < cnt; ++e) {
        const unsigned p = packed[s0 + e];
        const int src = (int)(p >> 2);
        const int t = (int)(p & 3u);
        const float val = hin[(size_t)src * kHid + j];
        a0 += (t == 0) ? val : 0.f;
        a1 += (t == 1) ? val : 0.f;
        a2 += (t == 2) ? val : 0.f;
        a3 += (t == 3) ? val : 0.f;
        d0 += (t == 0); d1 += (t == 1); d2 += (t == 2); d3 += (t == 3);
      }
      float* Sn = &S[nl * 512];
      Sn[j] = a0; Sn[128 + j] = a1; Sn[256 + j] = a2; Sn[384 + j] = a3;
      if (j == 0) { D[nl][0] = d0; D[nl][1] = d1; D[nl][2] = d2; D[nl][3] = d3; }
    }
  }
  __syncthreads();

  const int lane = tid & 31;
  const int jj = lane * 4;
  const int n0 = (tid >> 5) * 4;
  float acc[4][4] = {};
  const float4* __restrict__ W4 = (const float4*)W;
  for (int tk = 0; tk < 512; tk += 4) {
    const float4 w0 = W4[(size_t)(tk + 0) * 32 + lane];
    const float4 w1 = W4[(size_t)(tk + 1) * 32 + lane];
    const float4 w2 = W4[(size_t)(tk + 2) * 32 + lane];
    const float4 w3 = W4[(size_t)(tk + 3) * 32 + lane];
#pragma unroll
    for (int n = 0; n < 4; ++n) {
      const float4 s = *(const float4*)&S[(n0 + n) * 512 + tk];
      acc[n][0] += s.x * w0.x + s.y * w1.x + s.z * w2.x + s.w * w3.x;
      acc[n][1] += s.x * w0.y + s.y * w1.y + s.z * w2.y + s.w * w3.y;
      acc[n][2] += s.x * w0.z + s.y * w1.z + s.z * w2.z + s.w * w3.z;
      acc[n][3] += s.x * w0.w + s.y * w1.w + s.z * w2.w + s.w * w3.w;
    }
  }
  const float4 B0 = *(const float4*)&TB[0 * 128 + jj];
  const float4 B1 = *(const float4*)&TB[1 * 128 + jj];
  const float4 B2 = *(const float4*)&TB[2 * 128 + jj];
  const float4 B3 = *(const float4*)&TB[3 * 128 + jj];
#pragma unroll
  for (int n = 0; n < 4; ++n) {
    const int v = blockIdx.x * 32 + n0 + n;
    if (v < kNodes) {
      float4 o;
      const float d0 = (float)D[n0 + n][0], d1 = (float)D[n0 + n][1];
      const float d2 = (float)D[n0 + n][2], d3 = (float)D[n0 + n][3];
      o.x = acc[n][0] + d0 * B0.x + d1 * B1.x + d2 * B2.x + d3 * B3.x;
      o.y = acc[n][1] + d0 * B0.y + d1 * B1.y + d2 * B2.y + d3 * B3.y;
      o.z = acc[n][2] + d0 * B0.z + d1 * B1.z + d2 * B2.z + d3 * B3.z;
      o.w = acc[n][3] + d0 * B0.w + d1 * B1.w + d2 * B2.w + d3 * B3.w;
      *(float4*)&msg[(size_t)v * kHid + jj] = o;
    }
  }
}

__global__ __launch_bounds__(256, 2) void gru_fb_kernel(
    const float* __restrict__ msg,
    const float* __restrict__ hin,
    const float* __restrict__ K,
    const float* __restrict__ R,
    const float* __restrict__ gb,
    float* __restrict__ hout) {
  __shared__ float At[2][16][68];
  __shared__ float Bt[2][16][384];
  const int tid = threadIdx.x;
  const int node0 = blockIdx.x * 64;
  const int cg = tid >> 4;
  const int ng = tid & 15;

  float accZ[4][8] = {}, accR[4][8] = {}, accXH[4][8] = {}, accRH[4][8] = {};
  const float4* __restrict__ K4 = (const float4*)K;
  const float4* __restrict__ R4 = (const float4*)R;
  const int sn = tid >> 2;
  const int sj = tid & 3;

  for (int k0 = 0; k0 < 128; k0 += 16) {
    __syncthreads();
    {
      float4 vm = make_float4(0.f, 0.f, 0.f, 0.f);
      float4 vh = vm;
      const int node = node0 + sn;
      if (node < kNodes) {
        vm = *(const float4*)&msg[(size_t)node * kHid + k0 + sj * 4];
        vh = *(const float4*)&hin[(size_t)node * kHid + k0 + sj * 4];
      }
      At[0][sj * 4 + 0][sn] = vm.x; At[0][sj * 4 + 1][sn] = vm.y;
      At[0][sj * 4 + 2][sn] = vm.z; At[0][sj * 4 + 3][sn] = vm.w;
      At[1][sj * 4 + 0][sn] = vh.x; At[1][sj * 4 + 1][sn] = vh.y;
      At[1][sj * 4 + 2][sn] = vh.z; At[1][sj * 4 + 3][sn] = vh.w;
    }
#pragma unroll
    for (int i = 0; i < 6; ++i) {
      const int idx = tid + i * 256;
      const int row = idx / 96;
      const int c4 = idx - row * 96;
      *(float4*)&Bt[0][row][c4 * 4] = K4[(size_t)(k0 + row) * 96 + c4];
      *(float4*)&Bt[1][row][c4 * 4] = R4[(size_t)(k0 + row) * 96 + c4];
    }
    __syncthreads();

    for (int kk = 0; kk < 16; ++kk) {
      const float4 am4 = *(const float4*)&At[0][kk][ng * 4];
      const float4 ah4 = *(const float4*)&At[1][kk][ng * 4];
      const float am[4] = {am4.x, am4.y, am4.z, am4.w};
      const float ah[4] = {ah4.x, ah4.y, ah4.z, ah4.w};
      const int cb = cg * 8;
#pragma unroll
      for (int gset = 0; gset < 3; ++gset) {
        const int off = gset * 128 + cb;
        const float4 k0v = *(const float4*)&Bt[0][kk][off];
        const float4 k1v = *(const float4*)&Bt[0][kk][off + 4];
        const float4 r0v = *(const float4*)&Bt[1][kk][off];
        const float4 r1v = *(const float4*)&Bt[1][kk][off + 4];
        const float bk[8] = {k0v.x, k0v.y, k0v.z, k0v.w, k1v.x, k1v.y, k1v.z, k1v.w};
        const float br[8] = {r0v.x, r0v.y, r0v.z, r0v.w, r1v.x, r1v.y, r1v.z, r1v.w};
        if (gset == 0) {
#pragma unroll
          for (int n = 0; n < 4; ++n)
#pragma unroll
            for (int c = 0; c < 8; ++c) accZ[n][c] += am[n] * bk[c] + ah[n] * br[c];
        } else if (gset == 1) {
#pragma unroll
          for (int n = 0; n < 4; ++n)
#pragma unroll
            for (int c = 0; c < 8; ++c) accR[n][c] += am[n] * bk[c] + ah[n] * br[c];
        } else {
#pragma unroll
          for (int n = 0; n < 4; ++n)
#pragma unroll
            for (int c = 0; c < 8; ++c) {
              accXH[n][c] += am[n] * bk[c];
              accRH[n][c] += ah[n] * br[c];
            }
        }
      }
    }
  }

  const int cb = cg * 8;
#pragma unroll
  for (int n = 0; n < 4; ++n) {
    const int node = node0 + ng * 4 + n;
    if (node >= kNodes) continue;
    float o[8];
#pragma unroll
    for (int c = 0; c < 8; ++c) {
      const float z = sigf(accZ[n][c] + gb[cb + c] + gb[384 + cb + c]);
      const float r = sigf(accR[n][c] + gb[128 + cb + c] + gb[512 + cb + c]);
      const float hh = tanh_fast(accXH[n][c] + gb[256 + cb + c] +
                                 r * (accRH[n][c] + gb[640 + cb + c]));
      const float hp = hin[(size_t)node * kHid + cb + c];
      o[c] = z * hp + (1.f - z) * hh;
    }
    *(float4*)&hout[(size_t)node * kHid + cb]     = make_float4(o[0], o[1], o[2], o[3]);
    *(float4*)&hout[(size_t)node * kHid + cb + 4] = make_float4(o[4], o[5], o[6], o[7]);
  }
}

extern "C" void kernel_launch(void* const* d_in, const int* in_sizes, int n_in,
                              void* d_out, int out_size, void* d_ws, size_t ws_size,
                              hipStream_t stream) {
  const float* states = (const float*)d_in[0];
  const int*   edges  = (const int*)d_in[1];
  const float* W      = (const float*)d_in[2];
  const float* TB     = (const float*)d_in[3];
  const float* K      = (const float*)d_in[4];
  const float* R      = (const float*)d_in[5];
  const float* gb     = (const float*)d_in[6];
  float* out = (float*)d_out;

  if (ws_size < kWsFallback) return;

  char* ws = (char*)d_ws;
  int*      counts  = (int*)(ws + oCounts);
  int*      cursor  = (int*)(ws + oCursor);
  int*      bsums   = (int*)(ws + oBlockSums);
  uint16_t* bpack   = (uint16_t*)(ws + oBpack);
  unsigned* packed  = (unsigned*)(ws + oPacked);
  float*    msg     = (float*)(ws + oMsg);
  uint16_t* y16     = (uint16_t*)(ws + oY);
  uint32_t* y2      = (uint32_t*)(ws + oY);

  hipMemsetAsync(counts, 0, 200704, stream);
  count_kernel<<<kEdges / 256, 256, 0, stream>>>(edges, counts);
  scan1_kernel<<<kScanBlocks, 256, 0, stream>>>(counts, cursor, bsums);
  scan2_kernel<<<1, 256, 0, stream>>>(bsums);
  scan3_kernel<<<kScanBlocks, 256, 0, stream>>>(cursor, bsums);
  fill_kernel<<<kEdges / 256, 256, 0, stream>>>(edges, cursor, packed);

  if (ws_size >= kWsNeeded) {
    pack_b_kernel<<<448, 256, 0, stream>>>(K, R, W, bpack);
    const int tf_blocks  = ((kNodes + 511) / 512) * 8;  // 98*8 = 784
    const int gru_blocks = (kNodes + 127) / 128;        // 391
    const int ga_blocks  = kNodes / 4;                  // 12500
    // step 1
    transform_mfma<<<tf_blocks, 256, 0, stream>>>(states, bpack, TB, y16);
    gather_kernel<<<ga_blocks, 256, 0, stream>>>(y2, packed, cursor, counts, msg);
    gru_mfma<<<gru_blocks, 512, 0, stream>>>(msg, states, bpack, gb, out);
    // step 2 (in-place on d_out; see gru_mfma barrier note)
    transform_mfma<<<tf_blocks, 256, 0, stream>>>(out, bpack, TB, y16);
    gather_kernel<<<ga_blocks, 256, 0, stream>>>(y2, packed, cursor, counts, msg);
    gru_mfma<<<gru_blocks, 512, 0, stream>>>(msg, out, bpack, gb, out);
  } else {
    const int msg_blocks = (kNodes + 31) / 32;  // 1563
    const int gru_blocks = (kNodes + 63) / 64;  // 782
    message_fb_kernel<<<msg_blocks, 256, 0, stream>>>(states, packed, cursor,
                                                      counts, W, TB, msg);
    gru_fb_kernel<<<gru_blocks, 256, 0, stream>>>(msg, states, K, R, gb, out);
    message_fb_kernel<<<msg_blocks, 256, 0, stream>>>(out, packed, cursor,
                                                      counts, W, TB, msg);
    gru_fb_kernel<<<gru_blocks, 256, 0, stream>>>(msg, out, K, R, gb, out);
  }
}

// Round 10
// 431.976 us; speedup vs baseline: 1.2409x; 1.2409x over previous
//
#include <hip/hip_runtime.h>
#include <stdint.h>

namespace {
constexpr int kNodes = 50000;
constexpr int kEdges = 800000;
constexpr int kHid   = 128;
constexpr int kScanBlocks = (kNodes + 255) / 256;  // 196
constexpr int kBlocks64 = (kNodes + 63) / 64;      // 782

// workspace layout (bytes)
constexpr size_t oCounts    = 0;         // 200000 (in-degree per node)
constexpr size_t oCursor    = 200704;    // 200000 (scan -> row_end)
constexpr size_t oBlockSums = 401408;    // 784
constexpr size_t oBpack     = 402432;    // 655360 (packed MFMA B-frags)
constexpr size_t oPacked    = 1057792;   // 800000*4 = 3200000 (CSR edge list)
constexpr size_t oMsg      = 4257792;   // msg: bf16 [N][128] = 12.8 MB (fp32 in fallback)
constexpr size_t oY         = 29857792;  // 50000*512*2 = 51200000 (bf16 y)
constexpr size_t kWsNeeded   = oY + 51200000;  // 81,057,792
constexpr size_t kWsFallback = oY;             // fallback path doesn't use oY

// Bpack sub-offsets (bytes relative to oBpack)
constexpr size_t bKhi = 0,      bKlo = 98304,  bRhi = 196608,
                 bRlo = 294912, bWhi = 393216, bWlo = 524288;
}

typedef __attribute__((ext_vector_type(8))) short short8;
typedef __attribute__((ext_vector_type(4))) float f32x4;

union ABFrag { short8 v; uint16_t u[8]; uint4 q; };

__device__ __forceinline__ uint16_t f2bf(float x) {
  uint32_t u = __float_as_uint(x);
  return (uint16_t)((u + 0x7FFFu + ((u >> 16) & 1u)) >> 16);
}
__device__ __forceinline__ float bf2f(uint16_t h) {
  return __uint_as_float(((uint32_t)h) << 16);
}

__device__ __forceinline__ float fast_rcp(float x) {
#if __has_builtin(__builtin_amdgcn_rcpf)
  return __builtin_amdgcn_rcpf(x);
#else
  return 1.f / x;
#endif
}
__device__ __forceinline__ float fast_exp2(float x) {
#if __has_builtin(__builtin_amdgcn_exp2f)
  return __builtin_amdgcn_exp2f(x);
#else
  return exp2f(x);
#endif
}
__device__ __forceinline__ float sigf(float x) {
  return fast_rcp(1.f + fast_exp2(-1.4426950408889634f * x));
}
__device__ __forceinline__ float tanh_fast(float x) {
  x = fminf(fmaxf(x, -10.f), 10.f);
  const float t = fast_exp2(2.8853900817779268f * x);  // e^(2x)
  return (t - 1.f) * fast_rcp(t + 1.f);
}

// msg/y column swizzle: position p holds original column pi(p).
// p = g*64 + col16*4 + s  <->  pi(p) = g*64 + s*16 + col16  (bijection on [0,128))
__device__ __forceinline__ int swz_pi(int p) {
  return (p & 64) | ((p & 3) << 4) | ((p >> 2) & 15);
}

// ---------------- CSR build ----------------

__global__ __launch_bounds__(256) void count_kernel(const int* __restrict__ edges,
                                                    int* __restrict__ counts) {
  int e = blockIdx.x * 256 + threadIdx.x;
  if (e < kEdges) atomicAdd(&counts[edges[e * 3 + 2]], 1);
}

__global__ __launch_bounds__(256) void scan1_kernel(const int* __restrict__ counts,
                                                    int* __restrict__ cursor,
                                                    int* __restrict__ blocksums) {
  __shared__ int sd[256];
  const int t = threadIdx.x;
  const int i = blockIdx.x * 256 + t;
  int v = (i < kNodes) ? counts[i] : 0;
  sd[t] = v;
  __syncthreads();
  for (int off = 1; off < 256; off <<= 1) {
    int x = (t >= off) ? sd[t - off] : 0;
    __syncthreads();
    sd[t] += x;
    __syncthreads();
  }
  if (i < kNodes) cursor[i] = sd[t] - v;
  if (t == 255) blocksums[blockIdx.x] = sd[255];
}

__global__ __launch_bounds__(256) void scan2_kernel(int* __restrict__ blocksums) {
  __shared__ int sd[256];
  const int t = threadIdx.x;
  int v = (t < kScanBlocks) ? blocksums[t] : 0;
  sd[t] = v;
  __syncthreads();
  for (int off = 1; off < 256; off <<= 1) {
    int x = (t >= off) ? sd[t - off] : 0;
    __syncthreads();
    sd[t] += x;
    __syncthreads();
  }
  if (t < kScanBlocks) blocksums[t] = sd[t] - v;
}

__global__ __launch_bounds__(256) void scan3_kernel(int* __restrict__ cursor,
                                                    const int* __restrict__ blocksums) {
  const int i = blockIdx.x * 256 + threadIdx.x;
  if (i < kNodes) cursor[i] += blocksums[blockIdx.x];
}

__global__ __launch_bounds__(256) void fill_kernel(const int* __restrict__ edges,
                                                   int* __restrict__ cursor,
                                                   unsigned* __restrict__ packed) {
  int e = blockIdx.x * 256 + threadIdx.x;
  if (e < kEdges) {
    const int et  = edges[e * 3 + 0];
    const int src = edges[e * 3 + 1];
    const int tgt = edges[e * 3 + 2];
    const int pos = atomicAdd(&cursor[tgt], 1);
    packed[pos] = (unsigned)(src * 4 + et);
  }
  // after this kernel cursor[v] = row_end(v)
}

// ---------------- pack B operands into MFMA-frag order ----------------
// K (msg-side) k-rows permuted by swz_pi to match the swizzled msg layout.
__global__ __launch_bounds__(256) void pack_b_kernel(
    const float* __restrict__ K,   // [128][384]
    const float* __restrict__ R,   // [128][384]
    const float* __restrict__ W,   // [4][128][128]
    uint16_t* __restrict__ bp) {
  const int idx = blockIdx.x * 256 + threadIdx.x;
  uint16_t* khi = bp + bKhi / 2;
  uint16_t* klo = bp + bKlo / 2;
  uint16_t* rhi = bp + bRhi / 2;
  uint16_t* rlo = bp + bRlo / 2;
  uint16_t* whi = bp + bWhi / 2;
  uint16_t* wlo = bp + bWlo / 2;
  if (idx < 128 * 384) {
    const int k = idx / 384, c = idx % 384;
    const int ksrc = swz_pi(k);
    const int kt = k >> 5, quad = (k >> 3) & 3, j = k & 7;
    const int nt = c >> 4, ln = (c & 15) | (quad << 4);
    const size_t o = ((size_t)(kt * 24 + nt) * 64 + ln) * 8 + j;
    const float kv = K[ksrc * 384 + c];
    const float rv = R[k * 384 + c];
    const uint16_t kh = f2bf(kv), rh = f2bf(rv);
    khi[o] = kh; klo[o] = f2bf(kv - bf2f(kh));
    rhi[o] = rh; rlo[o] = f2bf(rv - bf2f(rh));
  } else if (idx < 128 * 384 + 128 * 512) {
    const int i2 = idx - 128 * 384;
    const int k = i2 / 512, c = i2 % 512;
    const int t = c >> 7, cc = c & 127;
    const float wv = W[((size_t)t * 128 + k) * 128 + cc];
    const int kt = k >> 5, quad = (k >> 3) & 3, j = k & 7;
    const int nt = c >> 4, ln = (c & 15) | (quad << 4);
    const size_t o = ((size_t)(kt * 32 + nt) * 64 + ln) * 8 + j;
    const uint16_t wh = f2bf(wv);
    whi[o] = wh; wlo[o] = f2bf(wv - bf2f(wh));
  }
}

__device__ __forceinline__ void split8(const float* p, ABFrag& hi, ABFrag& lo) {
  const float4 a0 = *(const float4*)p;
  const float4 a1 = *(const float4*)(p + 4);
  const float v[8] = {a0.x, a0.y, a0.z, a0.w, a1.x, a1.y, a1.z, a1.w};
#pragma unroll
  for (int j = 0; j < 8; ++j) {
    const uint16_t t = f2bf(v[j]);
    hi.u[j] = t; lo.u[j] = f2bf(v[j] - bf2f(t));
  }
}
__device__ __forceinline__ void conv8(const float* p, ABFrag& hi) {
  const float4 a0 = *(const float4*)p;
  const float4 a1 = *(const float4*)(p + 4);
  const float v[8] = {a0.x, a0.y, a0.z, a0.w, a1.x, a1.y, a1.z, a1.w};
#pragma unroll
  for (int j = 0; j < 8; ++j) hi.u[j] = f2bf(v[j]);
}

// ---------------- transform (MFMA): y = h @ W_t + TB, bf16 out (swizzled cols) ----------------
// ROUND-8 SHAPE (proven 58 µs): block = 64 nodes x 512 cols; wave w = type w:
// 64 nodes (4 M-tiles) x 128 cols. 3-term split. Swizzled coalesced stores.
__global__ __launch_bounds__(256, 2) void transform_mfma(
    const float* __restrict__ h,       // [N][128]
    const uint16_t* __restrict__ bp,
    const float* __restrict__ TB,      // [512]
    uint16_t* __restrict__ y16) {      // [N][512] bf16 (bias included, swizzled)
  const int tid = threadIdx.x;
  const int w = tid >> 6;              // type 0..3
  const int lane = tid & 63;
  const int col16 = lane & 15, quad = lane >> 4;
  const int node0 = blockIdx.x * 64;

  const uint4* __restrict__ Whi = (const uint4*)(bp + bWhi / 2);
  const uint4* __restrict__ Wlo = (const uint4*)(bp + bWlo / 2);

  bool mok[4];
#pragma unroll
  for (int m = 0; m < 4; ++m) mok[m] = (node0 + m * 16) < kNodes;

  f32x4 acc[8][4];
#pragma unroll
  for (int nt = 0; nt < 8; ++nt)
#pragma unroll
    for (int m = 0; m < 4; ++m) acc[nt][m] = (f32x4){0.f, 0.f, 0.f, 0.f};

  const float* hrow = h + (size_t)(node0 + col16) * kHid + quad * 8;

#pragma unroll
  for (int kt = 0; kt < 4; ++kt) {
    ABFrag ah[4], al[4];
#pragma unroll
    for (int m = 0; m < 4; ++m) {
      if (mok[m]) {
        split8(hrow + (size_t)m * 16 * kHid + kt * 32, ah[m], al[m]);
      } else {
        ah[m].q = make_uint4(0, 0, 0, 0); al[m].q = ah[m].q;
      }
    }
#pragma unroll
    for (int nt = 0; nt < 8; ++nt) {
      ABFrag bh, bl;
      bh.q = Whi[(size_t)(kt * 32 + w * 8 + nt) * 64 + lane];
      bl.q = Wlo[(size_t)(kt * 32 + w * 8 + nt) * 64 + lane];
#pragma unroll
      for (int m = 0; m < 4; ++m) {
        f32x4 c = acc[nt][m];
        c = __builtin_amdgcn_mfma_f32_16x16x32_bf16(ah[m].v, bh.v, c, 0, 0, 0);
        c = __builtin_amdgcn_mfma_f32_16x16x32_bf16(ah[m].v, bl.v, c, 0, 0, 0);
        c = __builtin_amdgcn_mfma_f32_16x16x32_bf16(al[m].v, bh.v, c, 0, 0, 0);
        acc[nt][m] = c;
      }
    }
  }

  // epilogue: swizzled coalesced stores. acc[nt=g*4+s][m][r] -> position
  // node*512 + w*128 + g*64 + col16*4 + s, with bias TB[original col].
#pragma unroll
  for (int g = 0; g < 2; ++g) {
    float bias[4];
#pragma unroll
    for (int s = 0; s < 4; ++s) bias[s] = TB[w * 128 + (g * 4 + s) * 16 + col16];
#pragma unroll
    for (int m = 0; m < 4; ++m) {
      if (!mok[m]) continue;
#pragma unroll
      for (int r = 0; r < 4; ++r) {
        const int node = node0 + m * 16 + quad * 4 + r;
        const uint32_t lo = (uint32_t)f2bf(acc[g * 4 + 0][m][r] + bias[0]) |
                            ((uint32_t)f2bf(acc[g * 4 + 1][m][r] + bias[1]) << 16);
        const uint32_t hi = (uint32_t)f2bf(acc[g * 4 + 2][m][r] + bias[2]) |
                            ((uint32_t)f2bf(acc[g * 4 + 3][m][r] + bias[3]) << 16);
        *(uint2*)&y16[(size_t)node * 512 + w * 128 + g * 64 + col16 * 4] =
            make_uint2(lo, hi);
      }
    }
  }
}

// ---------------- gather: msg16[v][p] = bf16( sum_e y[src_e*4+t_e][p] ) ----------------
// Accumulate fp32, store bf16 (bit-identical to gru's former conv8-of-fp32-sum).
__global__ __launch_bounds__(256) void gather_kernel(
    const uint32_t* __restrict__ y2,      // y as uint32 pairs: [row][64]
    const uint32_t* __restrict__ packed,
    const int* __restrict__ rowend,
    const int* __restrict__ counts,
    uint32_t* __restrict__ msg2) {        // msg bf16 pairs: [node][64]
  const int tid = threadIdx.x;
  const int lane = tid & 63;
  const int v = blockIdx.x * 4 + (tid >> 6);
  const int cnt = counts[v];
  const int s0 = rowend[v] - cnt;
  float a0 = 0.f, a1 = 0.f;
  int e = 0;
  for (; e + 8 <= cnt; e += 8) {
    uint32_t p[8], u[8];
#pragma unroll
    for (int i = 0; i < 8; ++i) p[i] = packed[s0 + e + i];
#pragma unroll
    for (int i = 0; i < 8; ++i) u[i] = y2[(size_t)p[i] * 64 + lane];
#pragma unroll
    for (int i = 0; i < 8; ++i) {
      a0 += __uint_as_float(u[i] << 16);
      a1 += __uint_as_float(u[i] & 0xFFFF0000u);
    }
  }
  for (; e < cnt; ++e) {
    const uint32_t p = packed[s0 + e];
    const uint32_t u = y2[(size_t)p * 64 + lane];
    a0 += __uint_as_float(u << 16);
    a1 += __uint_as_float(u & 0xFFFF0000u);
  }
  msg2[(size_t)v * 64 + lane] = (uint32_t)f2bf(a0) | ((uint32_t)f2bf(a1) << 16);
}

// ---------------- GRU (MFMA): ROUND-8 SHAPE (proven 57 µs) ----------------
// block = 64 nodes x all 128 h-cols; wave w = 64 nodes (4 M-tiles) x h-cols
// w*32..w*32+31. msg is bf16 (loads drop straight into A-frags); h-side 2-term
// split from fp32 hin (hi only), weights hi+lo.
// IN-PLACE HAZARD (hin == hout on step 2): every wave reads all 64 rows but
// writes only its own 32-column slice; __syncthreads() between K-loop and
// epilogue drains all waves' global reads before any store.
__global__ __launch_bounds__(256, 2) void gru_mfma(
    const uint16_t* __restrict__ msg16, // [N][128] bf16 (swizzled cols)
    const float* __restrict__ hin,      // [N][128]
    const uint16_t* __restrict__ bp,
    const float* __restrict__ gb,       // [2][384]
    float* __restrict__ hout) {
  const int tid = threadIdx.x;
  const int w = tid >> 6;              // h-col group: cols w*32..w*32+31
  const int lane = tid & 63;
  const int col16 = lane & 15, quad = lane >> 4;
  const int node0 = blockIdx.x * 64;

  const uint4* __restrict__ Khi = (const uint4*)(bp + bKhi / 2);
  const uint4* __restrict__ Klo = (const uint4*)(bp + bKlo / 2);
  const uint4* __restrict__ Rhi = (const uint4*)(bp + bRhi / 2);
  const uint4* __restrict__ Rlo = (const uint4*)(bp + bRlo / 2);

  bool mok[4];
#pragma unroll
  for (int m = 0; m < 4; ++m) mok[m] = (node0 + m * 16) < kNodes;

  f32x4 aZ[2][4], aR[2][4], aX[2][4], aH[2][4];  // [lnt][m-tile]
#pragma unroll
  for (int i = 0; i < 2; ++i)
#pragma unroll
    for (int m = 0; m < 4; ++m) {
      aZ[i][m] = (f32x4){0.f, 0.f, 0.f, 0.f};
      aR[i][m] = aZ[i][m]; aX[i][m] = aZ[i][m]; aH[i][m] = aZ[i][m];
    }

  const uint16_t* mrow = msg16 + (size_t)(node0 + col16) * kHid + quad * 8;
  const float* hrow = hin + (size_t)(node0 + col16) * kHid + quad * 8;

#pragma unroll
  for (int kt = 0; kt < 4; ++kt) {
    ABFrag mh[4], hh[4];
#pragma unroll
    for (int m = 0; m < 4; ++m) {
      if (mok[m]) {
        mh[m].q = *(const uint4*)(mrow + (size_t)m * 16 * kHid + kt * 32);
        conv8(hrow + (size_t)m * 16 * kHid + kt * 32, hh[m]);
      } else {
        mh[m].q = make_uint4(0, 0, 0, 0); hh[m].q = mh[m].q;
      }
    }
#pragma unroll
    for (int lnt = 0; lnt < 2; ++lnt) {
      const int ntc = w * 2 + lnt;           // 0..7
      const size_t oz = (size_t)(kt * 24 + ntc) * 64 + lane;
      const size_t orr = (size_t)(kt * 24 + 8 + ntc) * 64 + lane;
      const size_t oh = (size_t)(kt * 24 + 16 + ntc) * 64 + lane;
      ABFrag kzh, kzl, rzh, rzl, krh, krl, rrh, rrl, khh, khl, rhh, rhl;
      kzh.q = Khi[oz]; kzl.q = Klo[oz]; rzh.q = Rhi[oz]; rzl.q = Rlo[oz];
      krh.q = Khi[orr]; krl.q = Klo[orr]; rrh.q = Rhi[orr]; rrl.q = Rlo[orr];
      khh.q = Khi[oh]; khl.q = Klo[oh]; rhh.q = Rhi[oh]; rhl.q = Rlo[oh];
#pragma unroll
      for (int m = 0; m < 4; ++m) {
        f32x4 z = aZ[lnt][m];
        z = __builtin_amdgcn_mfma_f32_16x16x32_bf16(mh[m].v, kzh.v, z, 0, 0, 0);
        z = __builtin_amdgcn_mfma_f32_16x16x32_bf16(mh[m].v, kzl.v, z, 0, 0, 0);
        z = __builtin_amdgcn_mfma_f32_16x16x32_bf16(hh[m].v, rzh.v, z, 0, 0, 0);
        z = __builtin_amdgcn_mfma_f32_16x16x32_bf16(hh[m].v, rzl.v, z, 0, 0, 0);
        aZ[lnt][m] = z;
        f32x4 r = aR[lnt][m];
        r = __builtin_amdgcn_mfma_f32_16x16x32_bf16(mh[m].v, krh.v, r, 0, 0, 0);
        r = __builtin_amdgcn_mfma_f32_16x16x32_bf16(mh[m].v, krl.v, r, 0, 0, 0);
        r = __builtin_amdgcn_mfma_f32_16x16x32_bf16(hh[m].v, rrh.v, r, 0, 0, 0);
        r = __builtin_amdgcn_mfma_f32_16x16x32_bf16(hh[m].v, rrl.v, r, 0, 0, 0);
        aR[lnt][m] = r;
        f32x4 x = aX[lnt][m];
        x = __builtin_amdgcn_mfma_f32_16x16x32_bf16(mh[m].v, khh.v, x, 0, 0, 0);
        x = __builtin_amdgcn_mfma_f32_16x16x32_bf16(mh[m].v, khl.v, x, 0, 0, 0);
        aX[lnt][m] = x;
        f32x4 y = aH[lnt][m];
        y = __builtin_amdgcn_mfma_f32_16x16x32_bf16(hh[m].v, rhh.v, y, 0, 0, 0);
        y = __builtin_amdgcn_mfma_f32_16x16x32_bf16(hh[m].v, rhl.v, y, 0, 0, 0);
        aH[lnt][m] = y;
      }
    }
  }

  // all waves' reads of hin/msg are complete past this point (vmcnt drained)
  __syncthreads();

  // ---- epilogue (wave-column-local)
#pragma unroll
  for (int lnt = 0; lnt < 2; ++lnt) {
    const int c = (w * 2 + lnt) * 16 + col16;
    const float bz = gb[c] + gb[384 + c];
    const float br = gb[128 + c] + gb[512 + c];
    const float bx = gb[256 + c];
    const float bh = gb[640 + c];
#pragma unroll
    for (int m = 0; m < 4; ++m) {
      if (!mok[m]) continue;
#pragma unroll
      for (int r = 0; r < 4; ++r) {
        const int node = node0 + m * 16 + quad * 4 + r;
        const float hp = hin[(size_t)node * kHid + c];
        const float z = sigf(aZ[lnt][m][r] + bz);
        const float rr = sigf(aR[lnt][m][r] + br);
        const float hh = tanh_fast(aX[lnt][m][r] + bx + rr * (aH[lnt][m][r] + bh));
        hout[(size_t)node * kHid + c] = z * hp + (1.f - z) * hh;
      }
    }
  }
}

// ---------------- fallback path (only if ws too small) ----------------

__global__ __launch_bounds__(256, 2) void message_fb_kernel(
    const float* __restrict__ hin,
    const unsigned* __restrict__ packed,
    const int* __restrict__ rowend,
    const int* __restrict__ counts,
    const float* __restrict__ W,
    const float* __restrict__ TB,
    float* __restrict__ msg) {
  __shared__ float S[32 * 512];
  __shared__ int D[32][4];
  const int tid = threadIdx.x;
  {
    const int g = tid >> 7;
    const int j = tid & 127;
    for (int i = 0; i < 16; ++i) {
      const int nl = g * 16 + i;
      const int v = blockIdx.x * 32 + nl;
      if (v >= kNodes) break;
      const int cnt = counts[v];
      const int s0 = rowend[v] - cnt;
      float a0 = 0.f, a1 = 0.f, a2 = 0.f, a3 = 0.f;
      int d0 = 0, d1 = 0, d2 = 0, d3 = 0;
      for (int e = 0; e < cnt; ++e) {
        const unsigned p = packed[s0 + e];
        const int src = (int)(p >> 2);
        const int t = (int)(p & 3u);
        const float val = hin[(size_t)src * kHid + j];
        a0 += (t == 0) ? val : 0.f;
        a1 += (t == 1) ? val : 0.f;
        a2 += (t == 2) ? val : 0.f;
        a3 += (t == 3) ? val : 0.f;
        d0 += (t == 0); d1 += (t == 1); d2 += (t == 2); d3 += (t == 3);
      }
      float* Sn = &S[nl * 512];
      Sn[j] = a0; Sn[128 + j] = a1; Sn[256 + j] = a2; Sn[384 + j] = a3;
      if (j == 0) { D[nl][0] = d0; D[nl][1] = d1; D[nl][2] = d2; D[nl][3] = d3; }
    }
  }
  __syncthreads();

  const int lane = tid & 31;
  const int jj = lane * 4;
  const int n0 = (tid >> 5) * 4;
  float acc[4][4] = {};
  const float4* __restrict__ W4 = (const float4*)W;
  for (int tk = 0; tk < 512; tk += 4) {
    const float4 w0 = W4[(size_t)(tk + 0) * 32 + lane];
    const float4 w1 = W4[(size_t)(tk + 1) * 32 + lane];
    const float4 w2 = W4[(size_t)(tk + 2) * 32 + lane];
    const float4 w3 = W4[(size_t)(tk + 3) * 32 + lane];
#pragma unroll
    for (int n = 0; n < 4; ++n) {
      const float4 s = *(const float4*)&S[(n0 + n) * 512 + tk];
      acc[n][0] += s.x * w0.x + s.y * w1.x + s.z * w2.x + s.w * w3.x;
      acc[n][1] += s.x * w0.y + s.y * w1.y + s.z * w2.y + s.w * w3.y;
      acc[n][2] += s.x * w0.z + s.y * w1.z + s.z * w2.z + s.w * w3.z;
      acc[n][3] += s.x * w0.w + s.y * w1.w + s.z * w2.w + s.w * w3.w;
    }
  }
  const float4 B0 = *(const float4*)&TB[0 * 128 + jj];
  const float4 B1 = *(const float4*)&TB[1 * 128 + jj];
  const float4 B2 = *(const float4*)&TB[2 * 128 + jj];
  const float4 B3 = *(const float4*)&TB[3 * 128 + jj];
#pragma unroll
  for (int n = 0; n < 4; ++n) {
    const int v = blockIdx.x * 32 + n0 + n;
    if (v < kNodes) {
      float4 o;
      const float d0 = (float)D[n0 + n][0], d1 = (float)D[n0 + n][1];
      const float d2 = (float)D[n0 + n][2], d3 = (float)D[n0 + n][3];
      o.x = acc[n][0] + d0 * B0.x + d1 * B1.x + d2 * B2.x + d3 * B3.x;
      o.y = acc[n][1] + d0 * B0.y + d1 * B1.y + d2 * B2.y + d3 * B3.y;
      o.z = acc[n][2] + d0 * B0.z + d1 * B1.z + d2 * B2.z + d3 * B3.z;
      o.w = acc[n][3] + d0 * B0.w + d1 * B1.w + d2 * B2.w + d3 * B3.w;
      *(float4*)&msg[(size_t)v * kHid + jj] = o;
    }
  }
}

__global__ __launch_bounds__(256, 2) void gru_fb_kernel(
    const float* __restrict__ msg,
    const float* __restrict__ hin,
    const float* __restrict__ K,
    const float* __restrict__ R,
    const float* __restrict__ gb,
    float* __restrict__ hout) {
  __shared__ float At[2][16][68];
  __shared__ float Bt[2][16][384];
  const int tid = threadIdx.x;
  const int node0 = blockIdx.x * 64;
  const int cg = tid >> 4;
  const int ng = tid & 15;

  float accZ[4][8] = {}, accR[4][8] = {}, accXH[4][8] = {}, accRH[4][8] = {};
  const float4* __restrict__ K4 = (const float4*)K;
  const float4* __restrict__ R4 = (const float4*)R;
  const int sn = tid >> 2;
  const int sj = tid & 3;

  for (int k0 = 0; k0 < 128; k0 += 16) {
    __syncthreads();
    {
      float4 vm = make_float4(0.f, 0.f, 0.f, 0.f);
      float4 vh = vm;
      const int node = node0 + sn;
      if (node < kNodes) {
        vm = *(const float4*)&msg[(size_t)node * kHid + k0 + sj * 4];
        vh = *(const float4*)&hin[(size_t)node * kHid + k0 + sj * 4];
      }
      At[0][sj * 4 + 0][sn] = vm.x; At[0][sj * 4 + 1][sn] = vm.y;
      At[0][sj * 4 + 2][sn] = vm.z; At[0][sj * 4 + 3][sn] = vm.w;
      At[1][sj * 4 + 0][sn] = vh.x; At[1][sj * 4 + 1][sn] = vh.y;
      At[1][sj * 4 + 2][sn] = vh.z; At[1][sj * 4 + 3][sn] = vh.w;
    }
#pragma unroll
    for (int i = 0; i < 6; ++i) {
      const int idx = tid + i * 256;
      const int row = idx / 96;
      const int c4 = idx - row * 96;
      *(float4*)&Bt[0][row][c4 * 4] = K4[(size_t)(k0 + row) * 96 + c4];
      *(float4*)&Bt[1][row][c4 * 4] = R4[(size_t)(k0 + row) * 96 + c4];
    }
    __syncthreads();

    for (int kk = 0; kk < 16; ++kk) {
      const float4 am4 = *(const float4*)&At[0][kk][ng * 4];
      const float4 ah4 = *(const float4*)&At[1][kk][ng * 4];
      const float am[4] = {am4.x, am4.y, am4.z, am4.w};
      const float ah[4] = {ah4.x, ah4.y, ah4.z, ah4.w};
      const int cb = cg * 8;
#pragma unroll
      for (int gset = 0; gset < 3; ++gset) {
        const int off = gset * 128 + cb;
        const float4 k0v = *(const float4*)&Bt[0][kk][off];
        const float4 k1v = *(const float4*)&Bt[0][kk][off + 4];
        const float4 r0v = *(const float4*)&Bt[1][kk][off];
        const float4 r1v = *(const float4*)&Bt[1][kk][off + 4];
        const float bk[8] = {k0v.x, k0v.y, k0v.z, k0v.w, k1v.x, k1v.y, k1v.z, k1v.w};
        const float br[8] = {r0v.x, r0v.y, r0v.z, r0v.w, r1v.x, r1v.y, r1v.z, r1v.w};
        if (gset == 0) {
#pragma unroll
          for (int n = 0; n < 4; ++n)
#pragma unroll
            for (int c = 0; c < 8; ++c) accZ[n][c] += am[n] * bk[c] + ah[n] * br[c];
        } else if (gset == 1) {
#pragma unroll
          for (int n = 0; n < 4; ++n)
#pragma unroll
            for (int c = 0; c < 8; ++c) accR[n][c] += am[n] * bk[c] + ah[n] * br[c];
        } else {
#pragma unroll
          for (int n = 0; n < 4; ++n)
#pragma unroll
            for (int c = 0; c < 8; ++c) {
              accXH[n][c] += am[n] * bk[c];
              accRH[n][c] += ah[n] * br[c];
            }
        }
      }
    }
  }

  const int cb = cg * 8;
#pragma unroll
  for (int n = 0; n < 4; ++n) {
    const int node = node0 + ng * 4 + n;
    if (node >= kNodes) continue;
    float o[8];
#pragma unroll
    for (int c = 0; c < 8; ++c) {
      const float z = sigf(accZ[n][c] + gb[cb + c] + gb[384 + cb + c]);
      const float r = sigf(accR[n][c] + gb[128 + cb + c] + gb[512 + cb + c]);
      const float hh = tanh_fast(accXH[n][c] + gb[256 + cb + c] +
                                 r * (accRH[n][c] + gb[640 + cb + c]));
      const float hp = hin[(size_t)node * kHid + cb + c];
      o[c] = z * hp + (1.f - z) * hh;
    }
    *(float4*)&hout[(size_t)node * kHid + cb]     = make_float4(o[0], o[1], o[2], o[3]);
    *(float4*)&hout[(size_t)node * kHid + cb + 4] = make_float4(o[4], o[5], o[6], o[7]);
  }
}

extern "C" void kernel_launch(void* const* d_in, const int* in_sizes, int n_in,
                              void* d_out, int out_size, void* d_ws, size_t ws_size,
                              hipStream_t stream) {
  const float* states = (const float*)d_in[0];
  const int*   edges  = (const int*)d_in[1];
  const float* W      = (const float*)d_in[2];
  const float* TB     = (const float*)d_in[3];
  const float* K      = (const float*)d_in[4];
  const float* R      = (const float*)d_in[5];
  const float* gb     = (const float*)d_in[6];
  float* out = (float*)d_out;

  if (ws_size < kWsFallback) return;

  char* ws = (char*)d_ws;
  int*      counts  = (int*)(ws + oCounts);
  int*      cursor  = (int*)(ws + oCursor);
  int*      bsums   = (int*)(ws + oBlockSums);
  uint16_t* bpack   = (uint16_t*)(ws + oBpack);
  unsigned* packed  = (unsigned*)(ws + oPacked);
  float*    msgf    = (float*)(ws + oMsg);      // fallback: fp32 msg
  uint16_t* msg16   = (uint16_t*)(ws + oMsg);   // main: bf16 msg
  uint32_t* msg2    = (uint32_t*)(ws + oMsg);
  uint16_t* y16     = (uint16_t*)(ws + oY);
  uint32_t* y2      = (uint32_t*)(ws + oY);

  hipMemsetAsync(counts, 0, 200704, stream);
  count_kernel<<<kEdges / 256, 256, 0, stream>>>(edges, counts);
  scan1_kernel<<<kScanBlocks, 256, 0, stream>>>(counts, cursor, bsums);
  scan2_kernel<<<1, 256, 0, stream>>>(bsums);
  scan3_kernel<<<kScanBlocks, 256, 0, stream>>>(cursor, bsums);
  fill_kernel<<<kEdges / 256, 256, 0, stream>>>(edges, cursor, packed);

  if (ws_size >= kWsNeeded) {
    pack_b_kernel<<<448, 256, 0, stream>>>(K, R, W, bpack);
    const int ga_blocks = kNodes / 4;  // 12500
    // step 1
    transform_mfma<<<kBlocks64, 256, 0, stream>>>(states, bpack, TB, y16);
    gather_kernel<<<ga_blocks, 256, 0, stream>>>(y2, packed, cursor, counts, msg2);
    gru_mfma<<<kBlocks64, 256, 0, stream>>>(msg16, states, bpack, gb, out);
    // step 2 (in-place on d_out; see gru_mfma barrier note)
    transform_mfma<<<kBlocks64, 256, 0, stream>>>(out, bpack, TB, y16);
    gather_kernel<<<ga_blocks, 256, 0, stream>>>(y2, packed, cursor, counts, msg2);
    gru_mfma<<<kBlocks64, 256, 0, stream>>>(msg16, out, bpack, gb, out);
  } else {
    const int msg_blocks = (kNodes + 31) / 32;  // 1563
    const int gru_blocks = (kNodes + 63) / 64;  // 782
    message_fb_kernel<<<msg_blocks, 256, 0, stream>>>(states, packed, cursor,
                                                      counts, W, TB, msgf);
    gru_fb_kernel<<<gru_blocks, 256, 0, stream>>>(msgf, states, K, R, gb, out);
    message_fb_kernel<<<msg_blocks, 256, 0, stream>>>(out, packed, cursor,
                                                      counts, W, TB, msgf);
    gru_fb_kernel<<<gru_blocks, 256, 0, stream>>>(msgf, out, K, R, gb, out);
  }
}